// Round 8
// baseline (71.352 us; speedup 1.0000x reference)
//
#include <hip/hip_runtime.h>
#include <cfloat>
#include <cstdint>

#define BB    4              // batches
#define NN    8192           // points per cloud
#define NT    8              // rows (gt queries) per thread
#define TPB   256            // threads per block
#define NTILE (NT*TPB)       // 2048 rows per block
#define NBQ   (NN/NTILE)     // 4 row-tiles
#define MSL   64             // pred points (cols) per block
#define MS    (NN/MSL)       // 128 col slices
#define NPAIR (MSL/2)        // 32 col-pairs
#define NHW   (TPB/32)       // 8 half-waves per block
#define NGRP  (BB*NBQ)       // 16 (b,nb) groups
// ws layout (floats):
//   rowpart [NGRP][MS][NTILE]  = 4,194,304 f32 (16 MB)
//   colpart [NGRP][MS][MSL]    =   131,072 f32 (512 KB)
//   partial [1024]
#define ROWPART_SZ ((size_t)NGRP*MS*NTILE)
#define COLPART_SZ ((size_t)NGRP*MS*MSL)

static __device__ __forceinline__ float vmin3(float a, float b, float c) {
    float r;
    asm("v_min3_f32 %0, %1, %2, %3" : "=v"(r) : "v"(a), "v"(b), "v"(c));
    return r;
}
static __device__ __forceinline__ float vmin2(float a, float b) {
    float r;
    asm("v_min_f32 %0, %1, %2" : "=v"(r) : "v"(a), "v"(b));
    return r;
}

// One pass over the distance matrix. Block: 2048 rows (regs) x 64 cols (LDS).
// NO global atomics: each block stores row/col partial mins to a private
// coalesced slice of ws; reduce kernels finish min + sum.
__global__ __launch_bounds__(TPB) void chamfer_onepass_kernel(
    const float* __restrict__ pred, const float* __restrict__ gt,
    const float* __restrict__ coords, float* __restrict__ rowpart,
    float* __restrict__ colpart)
{
    const int b  = blockIdx.y;
    const int nb = blockIdx.x & (NBQ - 1);
    const int ms = blockIdx.x >> 2;          // 0..127
    const int grp = b * NBQ + nb;
    const size_t base = (size_t)b * 3 * NN;
    const float* gr = gt     + base;
    const float* pr = pred   + base;
    const float* cc = coords + base;

    __shared__ float4 tileE[NPAIR];          // col 2j   : (-2x,-2y,-2z,|q|^2)
    __shared__ float4 tileO[NPAIR];          // col 2j+1
    __shared__ float  colmin[NHW][MSL];      // per-half-wave col partial mins

    const int tid = threadIdx.x;

    // stage pred slice
    if (tid < MSL) {
        int m   = ms * MSL + tid;
        float x = cc[m]        + pr[m];
        float y = cc[NN + m]   + pr[NN + m];
        float z = cc[2*NN + m] + pr[2*NN + m];
        float4 v = make_float4(-2.f*x, -2.f*y, -2.f*z, fmaf(x, x, fmaf(y, y, z*z)));
        if (tid & 1) tileO[tid >> 1] = v; else tileE[tid >> 1] = v;
    }
    for (int j = tid; j < NHW * MSL; j += TPB) (&colmin[0][0])[j] = FLT_MAX;

    // gt rows in registers
    float px[NT], py[NT], pz[NT], sqn[NT], mv[NT];
    const int n0 = nb * NTILE + tid;
    #pragma unroll
    for (int k = 0; k < NT; ++k) {
        int n   = n0 + k * TPB;
        float x = cc[n]        + gr[n];
        float y = cc[NN + n]   + gr[NN + n];
        float z = cc[2*NN + n] + gr[2*NN + n];
        px[k] = x; py[k] = y; pz[k] = z;
        sqn[k] = fmaf(x, x, fmaf(y, y, z*z));
        mv[k]  = FLT_MAX;
    }
    __syncthreads();

    const int ll = tid & 31;                 // lane within half-wave
    float* cm = colmin[tid >> 5];

    int jp = ll;
    float4 a = tileE[jp];
    float4 c = tileO[jp];
    #pragma unroll 2
    for (int i = 0; i < NPAIR; ++i) {
        const int jn = (jp + 1) & (NPAIR - 1);
        float4 an = tileE[jn];               // prefetch next pair
        float4 cn = tileO[jn];
        float d0[NT], d1[NT];
        #pragma unroll
        for (int k = 0; k < NT; ++k) {
            float w0 = a.w + sqn[k];         // fold |p|^2 into the FMA addend
            float w1 = c.w + sqn[k];
            d0[k] = fmaf(px[k], a.x, fmaf(py[k], a.y, fmaf(pz[k], a.z, w0)));
            d1[k] = fmaf(px[k], c.x, fmaf(py[k], c.y, fmaf(pz[k], c.z, w1)));
            mv[k] = vmin3(mv[k], d0[k], d1[k]);
        }
        float t0 = vmin3(d0[0], d0[1], d0[2]);
        float u0 = vmin3(d0[3], d0[4], d0[5]);
        float s0 = vmin3(d0[6], d0[7], t0);
        float c0 = vmin2(s0, u0);
        float t1 = vmin3(d1[0], d1[1], d1[2]);
        float u1 = vmin3(d1[3], d1[4], d1[5]);
        float s1 = vmin3(d1[6], d1[7], t1);
        float c1 = vmin2(s1, u1);
        float2* slot = (float2*)&cm[2 * jp];
        float2 old = *slot;
        old.x = vmin2(old.x, c0);
        old.y = vmin2(old.y, c1);
        *slot = old;
        jp = jn; a = an; c = cn;
    }

    // row partial mins -> private slice (plain coalesced stores, no atomics)
    float* rp = rowpart + ((size_t)grp * MS + ms) * NTILE;
    #pragma unroll
    for (int k = 0; k < NT; ++k)
        rp[tid + k * TPB] = mv[k];

    __syncthreads();
    // col partial mins: combine 8 half-wave arrays -> private slice
    if (tid < MSL) {
        float v = vmin3(colmin[0][tid], colmin[1][tid], colmin[2][tid]);
        v = vmin3(v, colmin[3][tid], colmin[4][tid]);
        v = vmin3(v, colmin[5][tid], colmin[6][tid]);
        v = vmin2(v, colmin[7][tid]);
        colpart[((size_t)grp * MS + ms) * MSL + tid] = v;
    }
}

// reduce A: blocks 0..127 finish row mins (min over 128 ms slices),
// blocks 128..255 finish col mins (min over 4 nb groups); wave-sum partials.
__global__ __launch_bounds__(256) void chamfer_reduce_a(
    const float* __restrict__ rowpart, const float* __restrict__ colpart,
    float* __restrict__ partial)
{
    const int bid = blockIdx.x;
    const int tid = threadIdx.x;
    float val;
    if (bid < 128) {                          // rows: 32768 threads
        int t  = bid * 256 + tid;
        int g  = t >> 11;                     // (b,nb) group
        int rr = t & (NTILE - 1);
        const float* base = rowpart + (size_t)g * MS * NTILE + rr;
        float m = base[0];
        #pragma unroll 8
        for (int ms = 1; ms < MS; ++ms)
            m = vmin2(m, base[(size_t)ms * NTILE]);
        val = m;
    } else {                                  // cols: 32768 threads
        int t   = (bid - 128) * 256 + tid;
        int b   = t >> 13;
        int rem = t & (NN - 1);
        int ms  = rem >> 6, cl = rem & (MSL - 1);
        const float* base = colpart + ((size_t)(b * NBQ) * MS + ms) * MSL + cl;
        const size_t st = (size_t)MS * MSL;   // nb stride
        float m0 = base[0],      m1 = base[st];
        float m2 = base[2 * st], m3 = base[3 * st];
        val = vmin2(vmin2(m0, m1), vmin2(m2, m3));
    }
    #pragma unroll
    for (int off = 32; off > 0; off >>= 1)
        val += __shfl_down(val, off);
    if ((tid & 63) == 0)
        partial[bid * 4 + (tid >> 6)] = val;
}

// reduce B: fixed-order sum of 1024 wave partials
__global__ __launch_bounds__(256) void chamfer_reduce_b(
    const float* __restrict__ partial, float* __restrict__ out)
{
    const int tid = threadIdx.x;
    float s = (partial[tid] + partial[tid + 256])
            + (partial[tid + 512] + partial[tid + 768]);
    #pragma unroll
    for (int off = 32; off > 0; off >>= 1)
        s += __shfl_down(s, off);
    __shared__ float sm[4];
    if ((tid & 63) == 0) sm[tid >> 6] = s;
    __syncthreads();
    if (tid == 0) out[0] = ((sm[0] + sm[1]) + (sm[2] + sm[3])) * (1.0f / (float)BB);
}

extern "C" void kernel_launch(void* const* d_in, const int* in_sizes, int n_in,
                              void* d_out, int out_size, void* d_ws, size_t ws_size,
                              hipStream_t stream) {
    const float* pred   = (const float*)d_in[0];
    const float* gt     = (const float*)d_in[1];
    const float* coords = (const float*)d_in[2];
    float* rowpart = (float*)d_ws;
    float* colpart = rowpart + ROWPART_SZ;
    float* partial = colpart + COLPART_SZ;
    float* out     = (float*)d_out;

    dim3 grid(NBQ * MS, BB);                   // 512 x 4 = 2048 blocks
    chamfer_onepass_kernel<<<grid, TPB, 0, stream>>>(pred, gt, coords, rowpart, colpart);
    chamfer_reduce_a<<<256, 256, 0, stream>>>(rowpart, colpart, partial);
    chamfer_reduce_b<<<1, 256, 0, stream>>>(partial, out);
}

// Round 9
// 48.960 us; speedup vs baseline: 1.4573x; 1.4573x over previous
//
#include <hip/hip_runtime.h>
#include <cfloat>
#include <cstdint>

#define BB    4              // batches
#define NN    8192           // points per cloud
#define NT    8              // rows (gt queries) per thread
#define TPB   256            // threads per block
#define NTILE (NT*TPB)       // 2048 rows per block
#define NBQ   (NN/NTILE)     // 4 row-tiles
#define MSL   64             // cols (pred points) per slice
#define LPB   4              // slices per block -> 256 cols/block
#define NCG   (NN/(MSL*LPB)) // 32 col-groups
#define NPAIR (MSL/2)        // 32 col-pairs per slice
#define NHW   (TPB/32)       // 8 half-waves per block

static __device__ __forceinline__ float vmin3(float a, float b, float c) {
    float r;
    asm("v_min3_f32 %0, %1, %2, %3" : "=v"(r) : "v"(a), "v"(b), "v"(c));
    return r;
}
static __device__ __forceinline__ float vmin2(float a, float b) {
    float r;
    asm("v_min_f32 %0, %1, %2" : "=v"(r) : "v"(a), "v"(b));
    return r;
}

// order-preserving float<->uint mapping (finite floats)
__device__ __forceinline__ unsigned mapf(float f) {
    unsigned b = __float_as_uint(f);
    return b ^ ((unsigned)((int)b >> 31) | 0x80000000u);
}
__device__ __forceinline__ float unmapf(unsigned u) {
    unsigned b = u ^ (((u & 0x80000000u) != 0u) ? 0x80000000u : 0xFFFFFFFFu);
    return __uint_as_float(b);
}

// Persistent-ish one-pass: 512 blocks (2/CU, fully resident). Each block:
// 2048 rows in registers (loaded ONCE), loop over LPB=4 col-slices of 64.
// Next slice's 6 global streams are register-prefetched BEFORE the compute
// loop and LDS-written AFTER it (latency hidden under ~5600 cyc of FMA).
// Row mins accumulate in regs across slices -> one atomic pass at end.
__global__ __launch_bounds__(TPB, 2) void chamfer_onepass_kernel(
    const float* __restrict__ pred, const float* __restrict__ gt,
    const float* __restrict__ coords, unsigned* __restrict__ ws)
{
    const int b  = blockIdx.y;
    const int nb = blockIdx.x & (NBQ - 1);
    const int cg = blockIdx.x >> 2;          // 0..31 col-group
    const size_t base = (size_t)b * 3 * NN;
    const float* gr = gt     + base;
    const float* pr = pred   + base;
    const float* cc = coords + base;

    __shared__ float4 tileE[2][NPAIR];       // double-buffered col slices
    __shared__ float4 tileO[2][NPAIR];
    __shared__ float  colmin[NHW][MSL];      // per-half-wave col partial mins

    const int tid = threadIdx.x;
    const int colbase = cg * (LPB * MSL);

    // prologue: stage slice 0 into buf 0
    if (tid < MSL) {
        int m   = colbase + tid;
        float x = cc[m]        + pr[m];
        float y = cc[NN + m]   + pr[NN + m];
        float z = cc[2*NN + m] + pr[2*NN + m];
        float4 v = make_float4(-2.f*x, -2.f*y, -2.f*z, fmaf(x, x, fmaf(y, y, z*z)));
        if (tid & 1) tileO[0][tid >> 1] = v; else tileE[0][tid >> 1] = v;
    }
    for (int j = tid; j < NHW * MSL; j += TPB) (&colmin[0][0])[j] = FLT_MAX;

    // rows in registers (loaded once per block)
    float px[NT], py[NT], pz[NT], sqn[NT], mv[NT];
    const int n0 = nb * NTILE + tid;
    #pragma unroll
    for (int k = 0; k < NT; ++k) {
        int n   = n0 + k * TPB;
        float x = cc[n]        + gr[n];
        float y = cc[NN + n]   + gr[NN + n];
        float z = cc[2*NN + n] + gr[2*NN + n];
        px[k] = x; py[k] = y; pz[k] = z;
        sqn[k] = fmaf(x, x, fmaf(y, y, z*z));
        mv[k]  = FLT_MAX;
    }
    __syncthreads();

    const int ll = tid & 31;                 // lane within half-wave
    float* cm = colmin[tid >> 5];
    unsigned* wscol = ws + (size_t)BB * NN + (size_t)b * NN;

    int cur = 0;
    #pragma unroll 1
    for (int s = 0; s < LPB; ++s) {
        // issue next slice's global loads (regs only; consumed after loop)
        float r0, r1, r2, r3, r4, r5;
        const bool do_stage = (tid < MSL) && (s + 1 < LPB);
        if (do_stage) {
            int m = colbase + (s + 1) * MSL + tid;
            r0 = cc[m]; r1 = cc[NN + m]; r2 = cc[2*NN + m];
            r3 = pr[m]; r4 = pr[NN + m]; r5 = pr[2*NN + m];
        }

        // main 32-iter loop over buf[cur] (R5 inner loop, unchanged)
        int jp = ll;
        float4 a = tileE[cur][jp];
        float4 c = tileO[cur][jp];
        #pragma unroll 2
        for (int i = 0; i < NPAIR; ++i) {
            const int jn = (jp + 1) & (NPAIR - 1);
            float4 an = tileE[cur][jn];
            float4 cn = tileO[cur][jn];
            float d0[NT], d1[NT];
            #pragma unroll
            for (int k = 0; k < NT; ++k) {
                float w0 = a.w + sqn[k];
                float w1 = c.w + sqn[k];
                d0[k] = fmaf(px[k], a.x, fmaf(py[k], a.y, fmaf(pz[k], a.z, w0)));
                d1[k] = fmaf(px[k], c.x, fmaf(py[k], c.y, fmaf(pz[k], c.z, w1)));
                mv[k] = vmin3(mv[k], d0[k], d1[k]);
            }
            float t0 = vmin3(d0[0], d0[1], d0[2]);
            float u0 = vmin3(d0[3], d0[4], d0[5]);
            float s0 = vmin3(d0[6], d0[7], t0);
            float c0 = vmin2(s0, u0);
            float t1 = vmin3(d1[0], d1[1], d1[2]);
            float u1 = vmin3(d1[3], d1[4], d1[5]);
            float s1 = vmin3(d1[6], d1[7], t1);
            float c1 = vmin2(s1, u1);
            float2* slot = (float2*)&cm[2 * jp];
            float2 old = *slot;
            old.x = vmin2(old.x, c0);
            old.y = vmin2(old.y, c1);
            *slot = old;
            jp = jn; a = an; c = cn;
        }

        // write prefetched slice into the other buffer (vmcnt waits here,
        // after ~5600 cycles of compute -> latency fully hidden)
        if (do_stage) {
            float x = r0 + r3, y = r1 + r4, z = r2 + r5;
            float4 v = make_float4(-2.f*x, -2.f*y, -2.f*z,
                                   fmaf(x, x, fmaf(y, y, z*z)));
            if (tid & 1) tileO[cur ^ 1][tid >> 1] = v;
            else         tileE[cur ^ 1][tid >> 1] = v;
        }
        __syncthreads();                     // colmin RMWs + stage done

        // col write-out for slice s, then reinit colmin
        if (tid < MSL) {
            float v = vmin3(colmin[0][tid], colmin[1][tid], colmin[2][tid]);
            v = vmin3(v, colmin[3][tid], colmin[4][tid]);
            v = vmin3(v, colmin[5][tid], colmin[6][tid]);
            v = vmin2(v, colmin[7][tid]);
            atomicMin(&wscol[colbase + s * MSL + tid], mapf(v));
        }
        if (s + 1 < LPB) {
            for (int j = tid; j < NHW * MSL; j += TPB)
                (&colmin[0][0])[j] = FLT_MAX;
        }
        __syncthreads();                     // reinit visible before next RMWs
        cur ^= 1;
    }

    // row mins -> global atomics (once per block)
    unsigned* wsrow = ws + (size_t)b * NN;
    #pragma unroll
    for (int k = 0; k < NT; ++k)
        atomicMin(&wsrow[n0 + k * TPB], mapf(mv[k]));
}

// init mins to +inf in mapped-uint space (0xFFFFFFFF), 16384 uint4 stores
__global__ __launch_bounds__(256) void ws_init_kernel(unsigned* __restrict__ ws)
{
    ((uint4*)ws)[blockIdx.x * 256 + threadIdx.x] = make_uint4(~0u, ~0u, ~0u, ~0u);
}

// stage A: 64 blocks x 256 threads, uint4 per thread -> 64 partials
__global__ __launch_bounds__(256) void chamfer_reduce_a(
    const unsigned* __restrict__ ws, float* __restrict__ partial)
{
    int idx = blockIdx.x * 256 + threadIdx.x;
    const uint4* p = (const uint4*)ws;
    uint4 u = p[idx];
    float s = (unmapf(u.x) + unmapf(u.y)) + (unmapf(u.z) + unmapf(u.w));
    #pragma unroll
    for (int off = 32; off > 0; off >>= 1)
        s += __shfl_down(s, off);
    __shared__ float sm[4];
    if ((threadIdx.x & 63) == 0) sm[threadIdx.x >> 6] = s;
    __syncthreads();
    if (threadIdx.x == 0)
        partial[blockIdx.x] = (sm[0] + sm[1]) + (sm[2] + sm[3]);
}

__global__ __launch_bounds__(64) void chamfer_reduce_b(
    const float* __restrict__ partial, float* __restrict__ out)
{
    float s = partial[threadIdx.x];
    #pragma unroll
    for (int off = 32; off > 0; off >>= 1)
        s += __shfl_down(s, off);
    if (threadIdx.x == 0) out[0] = s * (1.0f / (float)BB);
}

extern "C" void kernel_launch(void* const* d_in, const int* in_sizes, int n_in,
                              void* d_out, int out_size, void* d_ws, size_t ws_size,
                              hipStream_t stream) {
    const float* pred   = (const float*)d_in[0];
    const float* gt     = (const float*)d_in[1];
    const float* coords = (const float*)d_in[2];
    unsigned*    wsu    = (unsigned*)d_ws;     // 2*B*N uints = 256 KB
    float*       part   = (float*)((char*)d_ws + (size_t)2 * BB * NN * sizeof(unsigned));
    float*       out    = (float*)d_out;

    ws_init_kernel<<<64, 256, 0, stream>>>(wsu);
    dim3 grid(NBQ * NCG, BB);                  // 128 x 4 = 512 blocks (2/CU)
    chamfer_onepass_kernel<<<grid, TPB, 0, stream>>>(pred, gt, coords, wsu);
    chamfer_reduce_a<<<64, 256, 0, stream>>>(wsu, part);
    chamfer_reduce_b<<<1, 64, 0, stream>>>(part, out);
}